// Round 1
// baseline (13236.642 us; speedup 1.0000x reference)
//
#include <hip/hip_runtime.h>

// ============================================================================
// 8-layer alternating-direction masked LSTM stack + embed + dense/softmax.
// Design:
//  - pack_frags: Wi/Wh/Wd f32 -> f16 MFMA-fragment-linear layout (once/call)
//  - embed_k:    gather emb1/emb2 -> X f16 [16384][256]
//  - per layer:  make_input (o[i-2]+o[i-1] -> X f16), gemm_xw (X@Wi -> xW f16),
//                lstm_layer (4 blocks = 4 CUs, 16 batch rows each, no sync)
//  - final_k:    (o6+o7)@Wd + bd -> softmax f32 -> d_out
// LSTM per step: 512 mfma_f32_16x16x32_f16 per CU; Wh split REG(kk0-2)/LDS(kk3-4)/
// L2-stream(kk5-7). h in LDS (f16, padded rows), c/h-carry in f32 regs.
// Workspace: ~84 MB.
// ============================================================================

typedef _Float16 f16;
typedef _Float16 f16x8 __attribute__((ext_vector_type(8)));
typedef _Float16 f16x4 __attribute__((ext_vector_type(4)));
typedef float    f32x4 __attribute__((ext_vector_type(4)));

#define DEVI static __device__ __forceinline__

DEVI float fast_sigmoid(float x) {
  return __builtin_amdgcn_rcpf(1.f + __builtin_amdgcn_exp2f(-1.44269504f * x));
}
DEVI float fast_tanh(float x) {
  // tanh(x) = 1 - 2/(1+e^{2x});  e^{2x} = 2^(2x*log2e)
  return 1.f - 2.f * __builtin_amdgcn_rcpf(1.f + __builtin_amdgcn_exp2f(2.88539008f * x));
}
// wave w owns coltiles {2w, 2w+1}; its 8 ntiles are quadrant q=j2>>1 (i,f,c,o),
// parity p=j2&1:  ntg = q*16 + 2w + p   (ntile = 16 gate-columns)
DEVI int ntg_of(int w, int j2) { return ((j2 >> 1) << 4) + 2 * w + (j2 & 1); }

// ---------------------------------------------------------------------------
// pack_frags: dst frag layout [L][kk][nt][lane][8 f16], one thread per
// (L,kk,nt,lane) 16B chunk. src is [L][256][ncols] f32 (ncols = nct*16).
// B-frag convention (16x16x32): lane l holds B[k = kk*32+(l>>4)*8+e][col = nt*16+(l&15)]
// ---------------------------------------------------------------------------
__global__ void pack_frags(const float* __restrict__ src, f16* __restrict__ dst, int nct) {
  const int idx  = blockIdx.x * 256 + threadIdx.x;
  const int lane = idx & 63;
  const int f    = idx >> 6;
  const int nt   = f % nct;
  const int g2   = f / nct;
  const int kk   = g2 & 7;
  const int L    = g2 >> 3;
  const int ncols = nct * 16;
  const float* s = src + (size_t)(L * 256 + kk * 32 + (lane >> 4) * 8) * ncols + nt * 16 + (lane & 15);
  f16x8 v;
#pragma unroll
  for (int e = 0; e < 8; ++e) v[e] = (f16)s[(size_t)e * ncols];
  *(f16x8*)(dst + (size_t)idx * 8) = v;
}

// ---------------------------------------------------------------------------
// embed: X[r][0:128] = emb1[wid[r]], X[r][128:256] = emb2[pid[r]]  (f16)
// ---------------------------------------------------------------------------
__global__ void embed_k(const int* __restrict__ wid, const int* __restrict__ pid,
                        const float* __restrict__ emb1, const float* __restrict__ emb2,
                        f16* __restrict__ X) {
  const int r = blockIdx.x;
  const int d = threadIdx.x;                 // 0..127
  const int wv = wid[r], pv = pid[r];
  X[r * 256 + d]       = (f16)emb1[wv * 128 + d];
  X[r * 256 + 128 + d] = (f16)emb2[pv * 128 + d];
}

// ---------------------------------------------------------------------------
// make_input: X = f16(a (+ b)), vectorized x4
// ---------------------------------------------------------------------------
__global__ void make_input(const float* __restrict__ a, const float* __restrict__ b,
                           f16* __restrict__ X, int two) {
  const int q = blockIdx.x * 256 + threadIdx.x;  // < 1048576
  float4 v = ((const float4*)a)[q];
  if (two) {
    float4 u = ((const float4*)b)[q];
    v.x += u.x; v.y += u.y; v.z += u.z; v.w += u.w;
  }
  f16x4 h; h[0] = (f16)v.x; h[1] = (f16)v.y; h[2] = (f16)v.z; h[3] = (f16)v.w;
  *(f16x4*)(X + (size_t)q * 4) = h;
}

// ---------------------------------------------------------------------------
// gemm_xw: xW[16384][1024] = X[16384][256] @ Wi  (Wi frag-packed in wipf)
// 512 thr (8 waves: 2 m-halves x 4 n-quarters), tile 128x128, K=256 one-shot.
// A staged in LDS (64KB) with XOR swizzle (col16 ^= row&7); B direct from L2.
// ---------------------------------------------------------------------------
__global__ __launch_bounds__(512, 2) void gemm_xw(const f16* __restrict__ X,
                                                  const f16* __restrict__ wipf,
                                                  f16* __restrict__ xW) {
  extern __shared__ char smem[];  // 65536 B : A tile [128][256] f16, swizzled
  const int tid = threadIdx.x, lane = tid & 63, w = tid >> 6;
  const int nb = blockIdx.x, mb = blockIdx.y;
  const char* xbase = (const char*)X + (size_t)mb * 128 * 512;
#pragma unroll
  for (int i = 0; i < 8; ++i) {
    const int row = i * 16 + (tid >> 5);     // 0..127
    const int c16 = tid & 31;                // 16B unit within 512B row
    const uint4 v = *(const uint4*)(xbase + row * 512 + c16 * 16);
    *(uint4*)(smem + row * 512 + ((c16 ^ (row & 7)) << 4)) = v;
  }
  __syncthreads();

  const int mh = w >> 2, nw = w & 3;
  const char* wipf_c = (const char*)wipf;
  f32x4 acc[4][2] = {};
#pragma unroll
  for (int kk = 0; kk < 8; ++kk) {
    const f16x8 b0 = *(const f16x8*)(wipf_c + ((size_t)(kk * 64 + nb * 8 + nw * 2 + 0) << 10) + (lane << 4));
    const f16x8 b1 = *(const f16x8*)(wipf_c + ((size_t)(kk * 64 + nb * 8 + nw * 2 + 1) << 10) + (lane << 4));
#pragma unroll
    for (int m2 = 0; m2 < 4; ++m2) {
      const int row = mh * 64 + m2 * 16 + (lane & 15);
      const f16x8 a = *(const f16x8*)(smem + row * 512 + (((kk * 4 + (lane >> 4)) ^ (row & 7)) << 4));
      acc[m2][0] = __builtin_amdgcn_mfma_f32_16x16x32_f16(a, b0, acc[m2][0], 0, 0, 0);
      acc[m2][1] = __builtin_amdgcn_mfma_f32_16x16x32_f16(a, b1, acc[m2][1], 0, 0, 0);
    }
  }
#pragma unroll
  for (int m2 = 0; m2 < 4; ++m2)
#pragma unroll
    for (int n2 = 0; n2 < 2; ++n2)
#pragma unroll
      for (int j = 0; j < 4; ++j) {
        const int r  = mb * 128 + mh * 64 + m2 * 16 + (lane >> 4) * 4 + j;
        const int cc = nb * 128 + nw * 32 + n2 * 16 + (lane & 15);
        xW[(size_t)r * 1024 + cc] = (f16)acc[m2][n2][j];
      }
}

// ---------------------------------------------------------------------------
// lstm_layer: one block = one CU = 16 batch rows, full layer (256 steps).
// 8 waves; wave w owns h-cols [32w,32w+32). Wh: REG kk0-2, LDS kk3-4, L2 kk5-7.
// h (f16) in LDS [16][264] (pad +8 to break bank conflicts); c, carried h in f32 regs.
// ---------------------------------------------------------------------------
__global__ __launch_bounds__(512, 2) void lstm_layer(
    const f16*  __restrict__ xW,    // [16384][1024] f16  (rows = b*256+t)
    const int*  __restrict__ wid,   // [64][256]
    const float* __restrict__ bias, // [1024] f32 (this layer)
    const f16*  __restrict__ whp,   // layer frag slab: [(kk*64+nt)*64+lane]*8 f16
    float* __restrict__ out,        // [64][256][256] f32 (rows = b*256+k)
    int reverse) {
  extern __shared__ char smem[];                   // 131072 (wh kk3,4) + 8448 (h)
  f16* h_lds = (f16*)(smem + 131072);              // [16][264]
  const int tid  = threadIdx.x;
  const int lane = tid & 63, w = tid >> 6;
  const int g    = blockIdx.x;                     // row group: b in [16g,16g+16)
  const int r0   = lane & 15;                      // col-in-tile / A-row
  const int rg   = lane >> 4;                      // row-group (C rows rg*4+j)
  const int ct0  = 2 * w;
  const char* whp_c = (const char*)whp;

  // stage Wh kk3,kk4 -> LDS (linear copy, frag layout is already conflict-free)
  {
    const char* src = whp_c + 196608;              // (3*64)*64*16
#pragma unroll
    for (int i = 0; i < 16; ++i) {
      const int off = i * 8192 + tid * 16;
      *(uint4*)(smem + off) = *(const uint4*)(src + off);
    }
  }
  for (int i = tid; i < 16 * 264; i += 512) h_lds[i] = (f16)0.f;

  // register-resident Wh kk0..2 (24 frags = 96 VGPR)
  f16x8 regB[24];
#pragma unroll
  for (int kk = 0; kk < 3; ++kk)
#pragma unroll
    for (int j2 = 0; j2 < 8; ++j2)
      regB[kk * 8 + j2] = *(const f16x8*)(whp_c + ((size_t)(kk * 64 + ntg_of(w, j2)) << 10) + (lane << 4));

  float bcol[8];
#pragma unroll
  for (int j2 = 0; j2 < 8; ++j2) bcol[j2] = bias[ntg_of(w, j2) * 16 + r0];

  float c[8], hreg[8];
#pragma unroll
  for (int i = 0; i < 8; ++i) { c[i] = 0.f; hreg[i] = 0.f; }

  __syncthreads();

#pragma unroll 1
  for (int k = 0; k < 256; ++k) {
    const int t_in = reverse ? (255 - k) : k;

    // issue xW + mask loads for this step (consumed after MFMA phase -> latency hidden)
    f16 xwv[32];
    int widv[4];
#pragma unroll
    for (int j = 0; j < 4; ++j) {
      const int b   = g * 16 + rg * 4 + j;
      const int row = (b << 8) + t_in;
      widv[j] = wid[row];
#pragma unroll
      for (int j2 = 0; j2 < 8; ++j2)
        xwv[j2 * 4 + j] = xW[(size_t)row * 1024 + ntg_of(w, j2) * 16 + r0];
    }

    // z = h @ Wh : 64 MFMA per wave
    f32x4 acc[8] = {};
#pragma unroll
    for (int kk = 0; kk < 8; ++kk) {
      const f16x8 a = *(const f16x8*)&h_lds[r0 * 264 + kk * 32 + rg * 8];
      if (kk < 3) {
#pragma unroll
        for (int j2 = 0; j2 < 8; ++j2)
          acc[j2] = __builtin_amdgcn_mfma_f32_16x16x32_f16(a, regB[kk * 8 + j2], acc[j2], 0, 0, 0);
      } else if (kk < 5) {
#pragma unroll
        for (int j2 = 0; j2 < 8; ++j2) {
          const f16x8 b8 = *(const f16x8*)(smem + ((size_t)((kk - 3) * 64 + ntg_of(w, j2)) << 10) + (lane << 4));
          acc[j2] = __builtin_amdgcn_mfma_f32_16x16x32_f16(a, b8, acc[j2], 0, 0, 0);
        }
      } else {
        f16x8 sb[8];
#pragma unroll
        for (int j2 = 0; j2 < 8; ++j2)
          sb[j2] = *(const f16x8*)(whp_c + ((size_t)(kk * 64 + ntg_of(w, j2)) << 10) + (lane << 4));
#pragma unroll
        for (int j2 = 0; j2 < 8; ++j2)
          acc[j2] = __builtin_amdgcn_mfma_f32_16x16x32_f16(a, sb[j2], acc[j2], 0, 0, 0);
      }
    }

    // gates (f32), state update, out store
#pragma unroll
    for (int p = 0; p < 2; ++p) {
#pragma unroll
      for (int j = 0; j < 4; ++j) {
        const int idx = p * 4 + j;
        const float zi = acc[p    ][j] + (float)xwv[(p    ) * 4 + j] + bcol[p];
        const float zf = acc[2 + p][j] + (float)xwv[(2 + p) * 4 + j] + bcol[2 + p];
        const float zc = acc[4 + p][j] + (float)xwv[(4 + p) * 4 + j] + bcol[4 + p];
        const float zo = acc[6 + p][j] + (float)xwv[(6 + p) * 4 + j] + bcol[6 + p];
        const float ig = fast_sigmoid(zi);
        const float fg = fast_sigmoid(zf);
        const float og = fast_sigmoid(zo);
        const float cb = fast_tanh(zc);
        const float cn = fg * c[idx] + ig * cb;
        const float hn = og * fast_tanh(cn);
        const bool  m  = (widv[j] != 0);
        c[idx] = m ? cn : c[idx];
        const float hv = m ? hn : hreg[idx];
        hreg[idx] = hv;
        const int b = g * 16 + rg * 4 + j;
        out[(size_t)(((b << 8) + k) << 8) + (ct0 + p) * 16 + r0] = hv;
      }
    }

    __syncthreads();   // all A-frag reads of this step done before overwriting h
#pragma unroll
    for (int p = 0; p < 2; ++p)
#pragma unroll
      for (int j = 0; j < 4; ++j)
        h_lds[(rg * 4 + j) * 264 + (ct0 + p) * 16 + r0] = (f16)hreg[p * 4 + j];
    __syncthreads();
  }
}

// ---------------------------------------------------------------------------
// final: softmax((o0+o1) @ Wd + bd) -> f32 out [16384][128]
// 8 waves x 16 rows each; A built from f32 adds, B frag-packed (wdpf).
// ---------------------------------------------------------------------------
__global__ __launch_bounds__(512, 2) void final_k(const float* __restrict__ o0,
                                                  const float* __restrict__ o1,
                                                  const f16* __restrict__ wdpf,
                                                  const float* __restrict__ bd,
                                                  float* __restrict__ outp) {
  const int tid = threadIdx.x, lane = tid & 63, w = tid >> 6;
  const int rbase = blockIdx.x * 128 + w * 16;
  const char* wdpf_c = (const char*)wdpf;

  f32x4 acc[8] = {};
#pragma unroll
  for (int kk = 0; kk < 8; ++kk) {
    const int r  = rbase + (lane & 15);
    const int k0 = kk * 32 + (lane >> 4) * 8;
    const float4* p0 = (const float4*)(o0 + (size_t)r * 256 + k0);
    const float4* p1 = (const float4*)(o1 + (size_t)r * 256 + k0);
    const float4 x0 = p0[0], x1 = p0[1], y0 = p1[0], y1 = p1[1];
    f16x8 a;
    a[0] = (f16)(x0.x + y0.x); a[1] = (f16)(x0.y + y0.y);
    a[2] = (f16)(x0.z + y0.z); a[3] = (f16)(x0.w + y0.w);
    a[4] = (f16)(x1.x + y1.x); a[5] = (f16)(x1.y + y1.y);
    a[6] = (f16)(x1.z + y1.z); a[7] = (f16)(x1.w + y1.w);
#pragma unroll
    for (int nt = 0; nt < 8; ++nt) {
      const f16x8 b = *(const f16x8*)(wdpf_c + ((size_t)(kk * 8 + nt) << 10) + (lane << 4));
      acc[nt] = __builtin_amdgcn_mfma_f32_16x16x32_f16(a, b, acc[nt], 0, 0, 0);
    }
  }

  float vb[8];
#pragma unroll
  for (int nt = 0; nt < 8; ++nt) vb[nt] = bd[nt * 16 + (lane & 15)];

#pragma unroll
  for (int j = 0; j < 4; ++j) {
    float v[8];
#pragma unroll
    for (int nt = 0; nt < 8; ++nt) v[nt] = acc[nt][j] + vb[nt];
    float mx = v[0];
#pragma unroll
    for (int nt = 1; nt < 8; ++nt) mx = fmaxf(mx, v[nt]);
#pragma unroll
    for (int m = 1; m < 16; m <<= 1) mx = fmaxf(mx, __shfl_xor(mx, m, 64));
    float s = 0.f;
#pragma unroll
    for (int nt = 0; nt < 8; ++nt) {
      v[nt] = __builtin_amdgcn_exp2f(1.44269504f * (v[nt] - mx));
      s += v[nt];
    }
#pragma unroll
    for (int m = 1; m < 16; m <<= 1) s += __shfl_xor(s, m, 64);
    const float rs = __builtin_amdgcn_rcpf(s);
    const int r = rbase + (lane >> 4) * 4 + j;
#pragma unroll
    for (int nt = 0; nt < 8; ++nt)
      outp[(size_t)r * 128 + nt * 16 + (lane & 15)] = v[nt] * rs;
  }
}

// ---------------------------------------------------------------------------
extern "C" void kernel_launch(void* const* d_in, const int* in_sizes, int n_in,
                              void* d_out, int out_size, void* d_ws, size_t ws_size,
                              hipStream_t stream) {
  const int*   wid  = (const int*)d_in[0];
  const int*   pid  = (const int*)d_in[1];
  const float* emb1 = (const float*)d_in[2];
  const float* emb2 = (const float*)d_in[3];
  const float* Wis  = (const float*)d_in[4];
  const float* Whs  = (const float*)d_in[5];
  const float* bs   = (const float*)d_in[6];
  const float* Wd   = (const float*)d_in[7];
  const float* bd   = (const float*)d_in[8];

  char* ws = (char*)d_ws;
  // workspace layout (bytes), total 83,951,616
  f16*   Whp  = (f16*)(ws + 0);          //  4,194,304
  f16*   Wipf = (f16*)(ws + 4194304);    //  4,194,304
  f16*   Wdpf = (f16*)(ws + 8388608);    //     65,536
  f16*   X    = (f16*)(ws + 8454144);    //  8,388,608
  f16*   xW   = (f16*)(ws + 16842752);   // 33,554,432
  float* o0   = (float*)(ws + 50397184); // 16,777,216
  float* o1   = (float*)(ws + 67174400); // 16,777,216

  hipFuncSetAttribute((const void*)lstm_layer, hipFuncAttributeMaxDynamicSharedMemorySize, 139520);
  hipFuncSetAttribute((const void*)gemm_xw,    hipFuncAttributeMaxDynamicSharedMemorySize, 65536);

  pack_frags<<<1024, 256, 0, stream>>>(Whs, Whp, 64);
  pack_frags<<<1024, 256, 0, stream>>>(Wis, Wipf, 64);
  pack_frags<<<16,   256, 0, stream>>>(Wd,  Wdpf, 8);
  embed_k<<<16384, 128, 0, stream>>>(wid, pid, emb1, emb2, X);

  float* obuf[2] = {o0, o1};
  for (int L = 0; L < 8; ++L) {
    if (L == 1)
      make_input<<<4096, 256, 0, stream>>>(o0, o0, X, 0);
    else if (L >= 2)
      make_input<<<4096, 256, 0, stream>>>(obuf[L & 1], obuf[(L - 1) & 1], X, 1);
    gemm_xw<<<dim3(8, 128), 512, 65536, stream>>>(X, Wipf + (size_t)L * 262144, xW);
    lstm_layer<<<4, 512, 139520, stream>>>(xW, wid, bs + L * 1024,
                                           Whp + (size_t)L * 262144, obuf[L & 1], L & 1);
  }
  final_k<<<128, 512, 0, stream>>>(o0, o1, Wdpf, bd, (float*)d_out);
}

// Round 2
// 11953.240 us; speedup vs baseline: 1.1074x; 1.1074x over previous
//
#include <hip/hip_runtime.h>

// ============================================================================
// 8-layer alternating-direction masked LSTM stack + embed + dense/softmax.
//  - pack_frags: Wi/Wh/Wd f32 -> f16 MFMA-fragment-linear layout (once/call)
//  - embed_k:    gather emb1/emb2 -> X f16 [16384][256]
//  - per layer:  make_input (o[i-2]+o[i-1] -> X f16), gemm_xw (X@Wi+b -> xW f16),
//                lstm_layer (4 blocks = 4 CUs, 16 batch rows each, no sync)
//  - final_k:    (o6+o7)@Wd + bd -> softmax f32 -> d_out
// LSTM per step: 512 mfma_f32_16x16x32_f16 per CU.
// Wh: REG kk0-3 (128 VGPR) / LDS kk4-5 (128KB) / L2-stream kk6-7 (shared 32-VGPR
// landing buffer, kk7 issued after kk6 consumed). h double-buffered in LDS;
// ONE raw s_barrier per step (lgkmcnt only, vmcnt stays in flight).
// ============================================================================

typedef _Float16 f16;
typedef _Float16 f16x8 __attribute__((ext_vector_type(8)));
typedef _Float16 f16x4 __attribute__((ext_vector_type(4)));
typedef float    f32x4 __attribute__((ext_vector_type(4)));

#define DEVI static __device__ __forceinline__

DEVI float fast_sigmoid(float x) {
  return __builtin_amdgcn_rcpf(1.f + __builtin_amdgcn_exp2f(-1.44269504f * x));
}
DEVI float fast_tanh(float x) {
  return 1.f - 2.f * __builtin_amdgcn_rcpf(1.f + __builtin_amdgcn_exp2f(2.88539008f * x));
}
// wave w owns coltiles {2w, 2w+1}; its 8 ntiles: quadrant q=j2>>1 (i,f,c,o),
// parity p=j2&1:  ntg = q*16 + 2w + p
DEVI int ntg_of(int w, int j2) { return ((j2 >> 1) << 4) + 2 * w + (j2 & 1); }

// ---------------------------------------------------------------------------
// pack_frags: dst frag layout [L][kk][nt][lane][8 f16].
// B-frag (16x16x32): lane l holds B[k=kk*32+(l>>4)*8+e][col=nt*16+(l&15)]
// ---------------------------------------------------------------------------
__global__ void pack_frags(const float* __restrict__ src, f16* __restrict__ dst, int nct) {
  const int idx  = blockIdx.x * 256 + threadIdx.x;
  const int lane = idx & 63;
  const int f    = idx >> 6;
  const int nt   = f % nct;
  const int g2   = f / nct;
  const int kk   = g2 & 7;
  const int L    = g2 >> 3;
  const int ncols = nct * 16;
  const float* s = src + (size_t)(L * 256 + kk * 32 + (lane >> 4) * 8) * ncols + nt * 16 + (lane & 15);
  f16x8 v;
#pragma unroll
  for (int e = 0; e < 8; ++e) v[e] = (f16)s[(size_t)e * ncols];
  *(f16x8*)(dst + (size_t)idx * 8) = v;
}

// ---------------------------------------------------------------------------
__global__ void embed_k(const int* __restrict__ wid, const int* __restrict__ pid,
                        const float* __restrict__ emb1, const float* __restrict__ emb2,
                        f16* __restrict__ X) {
  const int r = blockIdx.x;
  const int d = threadIdx.x;                 // 0..127
  const int wv = wid[r], pv = pid[r];
  X[r * 256 + d]       = (f16)emb1[wv * 128 + d];
  X[r * 256 + 128 + d] = (f16)emb2[pv * 128 + d];
}

// ---------------------------------------------------------------------------
__global__ void make_input(const float* __restrict__ a, const float* __restrict__ b,
                           f16* __restrict__ X, int two) {
  const int q = blockIdx.x * 256 + threadIdx.x;  // < 1048576
  float4 v = ((const float4*)a)[q];
  if (two) {
    float4 u = ((const float4*)b)[q];
    v.x += u.x; v.y += u.y; v.z += u.z; v.w += u.w;
  }
  f16x4 h; h[0] = (f16)v.x; h[1] = (f16)v.y; h[2] = (f16)v.z; h[3] = (f16)v.w;
  *(f16x4*)(X + (size_t)q * 4) = h;
}

// ---------------------------------------------------------------------------
// gemm_xw: xW[16384][1024] = X[16384][256] @ Wi + bias   (f16 out)
// ---------------------------------------------------------------------------
__global__ __launch_bounds__(512, 2) void gemm_xw(const f16* __restrict__ X,
                                                  const f16* __restrict__ wipf,
                                                  const float* __restrict__ bias,
                                                  f16* __restrict__ xW) {
  extern __shared__ char smem[];  // 65536 B : A tile [128][256] f16, swizzled
  const int tid = threadIdx.x, lane = tid & 63, w = tid >> 6;
  const int nb = blockIdx.x, mb = blockIdx.y;
  const char* xbase = (const char*)X + (size_t)mb * 128 * 512;
#pragma unroll
  for (int i = 0; i < 8; ++i) {
    const int row = i * 16 + (tid >> 5);
    const int c16 = tid & 31;
    const uint4 v = *(const uint4*)(xbase + row * 512 + c16 * 16);
    *(uint4*)(smem + row * 512 + ((c16 ^ (row & 7)) << 4)) = v;
  }
  __syncthreads();

  const int mh = w >> 2, nw = w & 3;
  const char* wipf_c = (const char*)wipf;
  const float vb0 = bias[nb * 128 + nw * 32 + (lane & 15)];
  const float vb1 = bias[nb * 128 + nw * 32 + 16 + (lane & 15)];
  f32x4 acc[4][2] = {};
#pragma unroll
  for (int kk = 0; kk < 8; ++kk) {
    const f16x8 b0 = *(const f16x8*)(wipf_c + ((size_t)(kk * 64 + nb * 8 + nw * 2 + 0) << 10) + (lane << 4));
    const f16x8 b1 = *(const f16x8*)(wipf_c + ((size_t)(kk * 64 + nb * 8 + nw * 2 + 1) << 10) + (lane << 4));
#pragma unroll
    for (int m2 = 0; m2 < 4; ++m2) {
      const int row = mh * 64 + m2 * 16 + (lane & 15);
      const f16x8 a = *(const f16x8*)(smem + row * 512 + (((kk * 4 + (lane >> 4)) ^ (row & 7)) << 4));
      acc[m2][0] = __builtin_amdgcn_mfma_f32_16x16x32_f16(a, b0, acc[m2][0], 0, 0, 0);
      acc[m2][1] = __builtin_amdgcn_mfma_f32_16x16x32_f16(a, b1, acc[m2][1], 0, 0, 0);
    }
  }
#pragma unroll
  for (int m2 = 0; m2 < 4; ++m2)
#pragma unroll
    for (int n2 = 0; n2 < 2; ++n2)
#pragma unroll
      for (int j = 0; j < 4; ++j) {
        const int r  = mb * 128 + mh * 64 + m2 * 16 + (lane >> 4) * 4 + j;
        const int cc = nb * 128 + nw * 32 + n2 * 16 + (lane & 15);
        xW[(size_t)r * 1024 + cc] = (f16)(acc[m2][n2][j] + (n2 ? vb1 : vb0));
      }
}

// ---------------------------------------------------------------------------
// lstm_layer: one block = one CU = 16 batch rows, full layer (256 steps).
// ---------------------------------------------------------------------------
__global__ __launch_bounds__(512, 2) void lstm_layer(
    const f16*  __restrict__ xW,    // [16384][1024] f16 (bias folded in)
    const int*  __restrict__ wid,   // [64][256]
    const f16*  __restrict__ whp,   // layer frag slab: kk*64KB + nt*1KB + lane*16B
    float* __restrict__ out,        // [64][256][256] f32
    int reverse) {
  extern __shared__ char smem[];                   // 131072 (Wh kk4,5) + 2*8448 (h dbuf)
  f16* hbuf = (f16*)(smem + 131072);               // 2 x [16][264] f16
  const int tid  = threadIdx.x;
  const int lane = tid & 63, w = tid >> 6;
  const int g    = blockIdx.x;
  const int r0   = lane & 15;
  const int rg   = lane >> 4;
  const int ct0  = 2 * w;
  const char* whp_c = (const char*)whp;

  // stage Wh kk4,kk5 -> LDS (frag layout is load-linear, conflict-free)
  {
    const char* src = whp_c + (4 << 16);
#pragma unroll
    for (int i = 0; i < 16; ++i) {
      const int off = i * 8192 + tid * 16;
      *(uint4*)(smem + off) = *(const uint4*)(src + off);
    }
  }
  for (int i = tid; i < 2 * 16 * 264; i += 512) hbuf[i] = (f16)0.f;

  // register-resident Wh kk0..3 (32 frags = 128 VGPR)
  f16x8 regB[32];
#pragma unroll
  for (int kk = 0; kk < 4; ++kk)
#pragma unroll
    for (int j2 = 0; j2 < 8; ++j2)
      regB[kk * 8 + j2] = *(const f16x8*)(whp_c + ((size_t)(kk * 64 + ntg_of(w, j2)) << 10) + (lane << 4));

  float c[8], hreg[8];
#pragma unroll
  for (int i = 0; i < 8; ++i) { c[i] = 0.f; hreg[i] = 0.f; }

  __syncthreads();

#pragma unroll 1
  for (int k = 0; k < 256; ++k) {
    const int t_in = reverse ? (255 - k) : k;
    const f16* hc = hbuf + (k & 1) * 4224;
    f16*       hn = hbuf + ((k & 1) ^ 1) * 4224;

    // 1) xW + mask loads (HBM/L2; consumed at gate phase -> max slack)
    f16 xwv[32];
    int widv[4];
#pragma unroll
    for (int j = 0; j < 4; ++j) {
      const int b   = g * 16 + rg * 4 + j;
      const int row = (b << 8) + t_in;
      widv[j] = wid[row];
#pragma unroll
      for (int j2 = 0; j2 < 8; ++j2)
        xwv[j2 * 4 + j] = xW[(size_t)row * 1024 + ntg_of(w, j2) * 16 + r0];
    }

    // 2) stream kk6 B-frags (L2)
    f16x8 sb6[8];
#pragma unroll
    for (int j2 = 0; j2 < 8; ++j2)
      sb6[j2] = *(const f16x8*)(whp_c + ((size_t)(6 * 64 + ntg_of(w, j2)) << 10) + (lane << 4));

    // 3) MFMA kk0-3 (REG) — A frags read on demand from LDS
    f32x4 acc[8] = {};
    f16x8 af[8];
#pragma unroll
    for (int kk = 0; kk < 4; ++kk) {
      af[kk] = *(const f16x8*)&hc[r0 * 264 + kk * 32 + rg * 8];
#pragma unroll
      for (int j2 = 0; j2 < 8; ++j2)
        acc[j2] = __builtin_amdgcn_mfma_f32_16x16x32_f16(af[kk], regB[kk * 8 + j2], acc[j2], 0, 0, 0);
    }

    // 4) MFMA kk6 (stream buf 1)
    af[6] = *(const f16x8*)&hc[r0 * 264 + 6 * 32 + rg * 8];
#pragma unroll
    for (int j2 = 0; j2 < 8; ++j2)
      acc[j2] = __builtin_amdgcn_mfma_f32_16x16x32_f16(af[6], sb6[j2], acc[j2], 0, 0, 0);

    // 5) issue kk7 stream loads (VMEM may not hoist above this point ->
    //    kk6/kk7 landing buffers can share registers)
    __builtin_amdgcn_sched_barrier(0x30F);
    f16x8 sb7[8];
#pragma unroll
    for (int j2 = 0; j2 < 8; ++j2)
      sb7[j2] = *(const f16x8*)(whp_c + ((size_t)(7 * 64 + ntg_of(w, j2)) << 10) + (lane << 4));

    // 6) MFMA kk4-5 (LDS) — covers kk7 load latency
#pragma unroll
    for (int kk = 4; kk < 6; ++kk) {
      af[kk] = *(const f16x8*)&hc[r0 * 264 + kk * 32 + rg * 8];
#pragma unroll
      for (int j2 = 0; j2 < 8; ++j2) {
        const f16x8 b8 = *(const f16x8*)(smem + ((size_t)((kk - 4) * 64 + ntg_of(w, j2)) << 10) + (lane << 4));
        acc[j2] = __builtin_amdgcn_mfma_f32_16x16x32_f16(af[kk], b8, acc[j2], 0, 0, 0);
      }
    }

    // 7) MFMA kk7
    af[7] = *(const f16x8*)&hc[r0 * 264 + 7 * 32 + rg * 8];
#pragma unroll
    for (int j2 = 0; j2 < 8; ++j2)
      acc[j2] = __builtin_amdgcn_mfma_f32_16x16x32_f16(af[7], sb7[j2], acc[j2], 0, 0, 0);

    // 8) gates (f32), state update, out store
#pragma unroll
    for (int p = 0; p < 2; ++p) {
#pragma unroll
      for (int j = 0; j < 4; ++j) {
        const int idx = p * 4 + j;
        const float zi = acc[p    ][j] + (float)xwv[(p    ) * 4 + j];
        const float zf = acc[2 + p][j] + (float)xwv[(2 + p) * 4 + j];
        const float zc = acc[4 + p][j] + (float)xwv[(4 + p) * 4 + j];
        const float zo = acc[6 + p][j] + (float)xwv[(6 + p) * 4 + j];
        const float ig = fast_sigmoid(zi);
        const float fg = fast_sigmoid(zf);
        const float og = fast_sigmoid(zo);
        const float cb = fast_tanh(zc);
        const float cn = fg * c[idx] + ig * cb;
        const float hn_ = og * fast_tanh(cn);
        const bool  m  = (widv[j] != 0);
        c[idx] = m ? cn : c[idx];
        const float hv = m ? hn_ : hreg[idx];
        hreg[idx] = hv;
        const int b = g * 16 + rg * 4 + j;
        out[(size_t)(((b << 8) + k) << 8) + (ct0 + p) * 16 + r0] = hv;
      }
    }

    // 9) publish h for step k+1 into the other buffer
#pragma unroll
    for (int p = 0; p < 2; ++p)
#pragma unroll
      for (int j = 0; j < 4; ++j)
        hn[(rg * 4 + j) * 264 + (ct0 + p) * 16 + r0] = (f16)hreg[p * 4 + j];

    // 10) ONE raw barrier: order LDS only; vmcnt (out stores, prefetches)
    //     stays in flight across it.
    __builtin_amdgcn_sched_barrier(0);
    asm volatile("s_waitcnt lgkmcnt(0)\n\ts_barrier" ::: "memory");
    __builtin_amdgcn_sched_barrier(0);
  }
}

// ---------------------------------------------------------------------------
// final: softmax((o6+o7) @ Wd + bd) -> f32 out [16384][128]
// ---------------------------------------------------------------------------
__global__ __launch_bounds__(512, 2) void final_k(const float* __restrict__ o0,
                                                  const float* __restrict__ o1,
                                                  const f16* __restrict__ wdpf,
                                                  const float* __restrict__ bd,
                                                  float* __restrict__ outp) {
  const int tid = threadIdx.x, lane = tid & 63, w = tid >> 6;
  const int rbase = blockIdx.x * 128 + w * 16;
  const char* wdpf_c = (const char*)wdpf;

  f32x4 acc[8] = {};
#pragma unroll
  for (int kk = 0; kk < 8; ++kk) {
    const int r  = rbase + (lane & 15);
    const int k0 = kk * 32 + (lane >> 4) * 8;
    const float4* p0 = (const float4*)(o0 + (size_t)r * 256 + k0);
    const float4* p1 = (const float4*)(o1 + (size_t)r * 256 + k0);
    const float4 x0 = p0[0], x1 = p0[1], y0 = p1[0], y1 = p1[1];
    f16x8 a;
    a[0] = (f16)(x0.x + y0.x); a[1] = (f16)(x0.y + y0.y);
    a[2] = (f16)(x0.z + y0.z); a[3] = (f16)(x0.w + y0.w);
    a[4] = (f16)(x1.x + y1.x); a[5] = (f16)(x1.y + y1.y);
    a[6] = (f16)(x1.z + y1.z); a[7] = (f16)(x1.w + y1.w);
#pragma unroll
    for (int nt = 0; nt < 8; ++nt) {
      const f16x8 b = *(const f16x8*)(wdpf_c + ((size_t)(kk * 8 + nt) << 10) + (lane << 4));
      acc[nt] = __builtin_amdgcn_mfma_f32_16x16x32_f16(a, b, acc[nt], 0, 0, 0);
    }
  }

  float vb[8];
#pragma unroll
  for (int nt = 0; nt < 8; ++nt) vb[nt] = bd[nt * 16 + (lane & 15)];

#pragma unroll
  for (int j = 0; j < 4; ++j) {
    float v[8];
#pragma unroll
    for (int nt = 0; nt < 8; ++nt) v[nt] = acc[nt][j] + vb[nt];
    float mx = v[0];
#pragma unroll
    for (int nt = 1; nt < 8; ++nt) mx = fmaxf(mx, v[nt]);
#pragma unroll
    for (int m = 1; m < 16; m <<= 1) mx = fmaxf(mx, __shfl_xor(mx, m, 64));
    float s = 0.f;
#pragma unroll
    for (int nt = 0; nt < 8; ++nt) {
      v[nt] = __builtin_amdgcn_exp2f(1.44269504f * (v[nt] - mx));
      s += v[nt];
    }
#pragma unroll
    for (int m = 1; m < 16; m <<= 1) s += __shfl_xor(s, m, 64);
    const float rs = __builtin_amdgcn_rcpf(s);
    const int r = rbase + (lane >> 4) * 4 + j;
#pragma unroll
    for (int nt = 0; nt < 8; ++nt)
      outp[(size_t)r * 128 + nt * 16 + (lane & 15)] = v[nt] * rs;
  }
}

// ---------------------------------------------------------------------------
extern "C" void kernel_launch(void* const* d_in, const int* in_sizes, int n_in,
                              void* d_out, int out_size, void* d_ws, size_t ws_size,
                              hipStream_t stream) {
  const int*   wid  = (const int*)d_in[0];
  const int*   pid  = (const int*)d_in[1];
  const float* emb1 = (const float*)d_in[2];
  const float* emb2 = (const float*)d_in[3];
  const float* Wis  = (const float*)d_in[4];
  const float* Whs  = (const float*)d_in[5];
  const float* bs   = (const float*)d_in[6];
  const float* Wd   = (const float*)d_in[7];
  const float* bd   = (const float*)d_in[8];

  char* ws = (char*)d_ws;
  f16*   Whp  = (f16*)(ws + 0);          //  4,194,304
  f16*   Wipf = (f16*)(ws + 4194304);    //  4,194,304
  f16*   Wdpf = (f16*)(ws + 8388608);    //     65,536
  f16*   X    = (f16*)(ws + 8454144);    //  8,388,608
  f16*   xW   = (f16*)(ws + 16842752);   // 33,554,432
  float* o0   = (float*)(ws + 50397184); // 16,777,216
  float* o1   = (float*)(ws + 67174400); // 16,777,216

  hipFuncSetAttribute((const void*)lstm_layer, hipFuncAttributeMaxDynamicSharedMemorySize, 147968);
  hipFuncSetAttribute((const void*)gemm_xw,    hipFuncAttributeMaxDynamicSharedMemorySize, 65536);

  pack_frags<<<1024, 256, 0, stream>>>(Whs, Whp, 64);
  pack_frags<<<1024, 256, 0, stream>>>(Wis, Wipf, 64);
  pack_frags<<<16,   256, 0, stream>>>(Wd,  Wdpf, 8);
  embed_k<<<16384, 128, 0, stream>>>(wid, pid, emb1, emb2, X);

  float* obuf[2] = {o0, o1};
  for (int L = 0; L < 8; ++L) {
    if (L == 1)
      make_input<<<4096, 256, 0, stream>>>(o0, o0, X, 0);
    else if (L >= 2)
      make_input<<<4096, 256, 0, stream>>>(obuf[L & 1], obuf[(L - 1) & 1], X, 1);
    gemm_xw<<<dim3(8, 128), 512, 65536, stream>>>(X, Wipf + (size_t)L * 262144, bs + L * 1024, xW);
    lstm_layer<<<4, 512, 147968, stream>>>(xW, wid, Whp + (size_t)L * 262144, obuf[L & 1], L & 1);
  }
  final_k<<<128, 512, 0, stream>>>(o0, o1, Wdpf, bd, (float*)d_out);
}